// Round 1
// baseline (95.320 us; speedup 1.0000x reference)
//
#include <hip/hip_runtime.h>

#define NN 50000
#define NE 100000
#define D 64

__global__ void init_last_edge(int* __restrict__ last_edge, int n) {
    int i = blockIdx.x * blockDim.x + threadIdx.x;
    if (i < n) last_edge[i] = -1;
}

__global__ void compute_last_edge(const int* __restrict__ edges,
                                  int* __restrict__ last_edge, int n_edges) {
    int e = blockIdx.x * blockDim.x + threadIdx.x;
    if (e < n_edges) {
        int dst = edges[e * 3 + 2];
        atomicMax(&last_edge[dst], e);
    }
}

__global__ __launch_bounds__(256) void rgcn_out(
    const float* __restrict__ h,
    const int*   __restrict__ edges,
    const float* __restrict__ weight,   // [64][64][64]
    const float* __restrict__ wself,    // [64][64]
    const int*   __restrict__ last_edge,
    float*       __restrict__ out)
{
    __shared__ float lds_wself[D * D];
    // cooperative vectorized load of W_self into LDS (16 KiB)
    for (int t = threadIdx.x; t < D * D / 4; t += blockDim.x) {
        reinterpret_cast<float4*>(lds_wself)[t] =
            reinterpret_cast<const float4*>(wself)[t];
    }
    __syncthreads();

    const int wave = threadIdx.x >> 6;   // 4 waves/block, 1 node/wave
    const int lane = threadIdx.x & 63;   // lane = output column o
    const int node = blockIdx.x * 4 + wave;
    if (node >= NN) return;

    const float hv = h[node * D + lane];
    const int le = last_edge[node];      // wave-uniform branch below

    float acc_agg = 0.f;
    if (le >= 0) {
        const int s = edges[le * 3 + 0];
        const int r = edges[le * 3 + 1];
        const float hs = h[s * D + lane];
        const float* __restrict__ W = weight + (size_t)r * D * D;
        #pragma unroll
        for (int i = 0; i < D; ++i) {
            float b = __shfl(hs, i, 64);
            acc_agg = fmaf(b, W[i * D + lane], acc_agg);  // coalesced 256B/wave
        }
    }

    float acc_self = 0.f;
    #pragma unroll
    for (int i = 0; i < D; ++i) {
        float a = __shfl(hv, i, 64);
        acc_self = fmaf(a, lds_wself[i * D + lane], acc_self); // 2-way bank alias: free
    }

    out[node * D + lane] = acc_self + acc_agg;
}

extern "C" void kernel_launch(void* const* d_in, const int* in_sizes, int n_in,
                              void* d_out, int out_size, void* d_ws, size_t ws_size,
                              hipStream_t stream) {
    const float* h     = (const float*)d_in[0];
    const int*   edges = (const int*)d_in[1];
    const float* weight = (const float*)d_in[2];
    const float* wself  = (const float*)d_in[3];
    float* out = (float*)d_out;
    int* last_edge = (int*)d_ws;   // 50000 * 4 B = 200 KB scratch

    init_last_edge<<<(NN + 255) / 256, 256, 0, stream>>>(last_edge, NN);
    compute_last_edge<<<(NE + 255) / 256, 256, 0, stream>>>(edges, last_edge, NE);
    rgcn_out<<<(NN + 3) / 4, 256, 0, stream>>>(h, edges, weight, wself, last_edge, out);
}

// Round 2
// 52.224 us; speedup vs baseline: 1.8252x; 1.8252x over previous
//
#include <hip/hip_runtime.h>

#define NN 50000
#define NE 100000
#define NREL 64
#define D 64
#define BPR 16                               // blocks per relation
#define NPB ((NN + BPR - 1) / BPR)           // nodes scanned per rel-block = 3125
#define NSELF 64                             // self-only blocks
#define NPS ((NN + NSELF - 1) / NSELF)       // 782
#define LCAP 512

__global__ void k_lastedge(const int* __restrict__ edges, int* __restrict__ last_edge) {
    int e = blockIdx.x * blockDim.x + threadIdx.x;
    if (e < NE) atomicMax(&last_edge[edges[e * 3 + 2]], e);
}

__global__ void k_relsrc(const int* __restrict__ edges, const int* __restrict__ last_edge,
                         int* __restrict__ relv, int* __restrict__ srcv) {
    int v = blockIdx.x * blockDim.x + threadIdx.x;
    if (v < NN) {
        int le = last_edge[v];
        int r = -1, s = 0;
        if (le >= 0) { r = edges[le * 3 + 1]; s = edges[le * 3 + 0]; }
        relv[v] = r;
        srcv[v] = s;
    }
}

__device__ __forceinline__ float bcast(float x, int i) {
    return __int_as_float(__builtin_amdgcn_readlane(__float_as_int(x), i));
}

__global__ __launch_bounds__(512, 8) void k_main(
    const float* __restrict__ h, const float* __restrict__ weight,
    const float* __restrict__ wself, const int* __restrict__ relv,
    const int* __restrict__ srcv, float* __restrict__ out)
{
    __shared__ float lds_w[D * D];     // W[r]      (16 KiB)
    __shared__ float lds_ws[D * D];    // W_self    (16 KiB)
    __shared__ int   lds_list[LCAP];
    __shared__ int   lds_cnt;

    const int lane = threadIdx.x & 63;
    const int wave = threadIdx.x >> 6;
    const bool isRel = blockIdx.x < NREL * BPR;

    if (threadIdx.x == 0) lds_cnt = 0;

    // stage W_self (all blocks need it)
    for (int t = threadIdx.x; t < D * D / 4; t += 512)
        reinterpret_cast<float4*>(lds_ws)[t] = reinterpret_cast<const float4*>(wself)[t];

    int r = -1, start, count;
    if (isRel) {
        r = blockIdx.x / BPR;
        int c = blockIdx.x % BPR;
        start = c * NPB;
        count = min(NPB, NN - start);
        const float4* wsrc = reinterpret_cast<const float4*>(weight + (size_t)r * D * D);
        for (int t = threadIdx.x; t < D * D / 4; t += 512)
            reinterpret_cast<float4*>(lds_w)[t] = wsrc[t];
    } else {
        int c = blockIdx.x - NREL * BPR;
        start = c * NPS;
        count = min(NPS, NN - start);
        if (count < 0) count = 0;
    }
    __syncthreads();

    // scan phase: collect matching nodes into LDS list
    for (int t = threadIdx.x; t < count; t += 512) {
        int v = start + t;
        if (relv[v] == r) {
            int p = atomicAdd(&lds_cnt, 1);
            if (p < LCAP) lds_list[p] = v;
        }
    }
    __syncthreads();
    const int cnt = min(lds_cnt, LCAP);

    // process phase: 4 nodes per wave-iteration
    for (int gi = wave; gi * 4 < cnt; gi += 8) {
        const int g = gi * 4;
        const int nact = min(4, cnt - g);

        int v[4];
        #pragma unroll
        for (int j = 0; j < 4; ++j)
            v[j] = (j < nact) ? lds_list[g + j] : lds_list[g];

        float hv[4], hs[4];
        #pragma unroll
        for (int j = 0; j < 4; ++j) {
            hv[j] = h[(size_t)v[j] * D + lane];
            hs[j] = isRel ? h[(size_t)srcv[v[j]] * D + lane] : 0.f;
        }

        float acc[4]  = {0.f, 0.f, 0.f, 0.f};
        float accS[4] = {0.f, 0.f, 0.f, 0.f};

        if (isRel) {
            #pragma unroll
            for (int i = 0; i < D; ++i) {
                const float w  = lds_w[i * D + lane];
                const float ws = lds_ws[i * D + lane];
                #pragma unroll
                for (int j = 0; j < 4; ++j) {
                    acc[j]  = fmaf(bcast(hs[j], i), w,  acc[j]);
                    accS[j] = fmaf(bcast(hv[j], i), ws, accS[j]);
                }
            }
        } else {
            #pragma unroll
            for (int i = 0; i < D; ++i) {
                const float ws = lds_ws[i * D + lane];
                #pragma unroll
                for (int j = 0; j < 4; ++j)
                    accS[j] = fmaf(bcast(hv[j], i), ws, accS[j]);
            }
        }

        #pragma unroll
        for (int j = 0; j < 4; ++j)
            if (j < nact) out[(size_t)v[j] * D + lane] = acc[j] + accS[j];
    }
}

extern "C" void kernel_launch(void* const* d_in, const int* in_sizes, int n_in,
                              void* d_out, int out_size, void* d_ws, size_t ws_size,
                              hipStream_t stream) {
    const float* h      = (const float*)d_in[0];
    const int*   edges  = (const int*)d_in[1];
    const float* weight = (const float*)d_in[2];
    const float* wself  = (const float*)d_in[3];
    float* out = (float*)d_out;

    int* last_edge = (int*)d_ws;                    // [0, 200KB)
    int* relv      = (int*)((char*)d_ws + 200 * 1024);  // [200KB, 400KB)
    int* srcv      = (int*)((char*)d_ws + 400 * 1024);  // [400KB, 600KB)

    hipMemsetAsync(last_edge, 0xFF, NN * sizeof(int), stream);   // -1
    k_lastedge<<<(NE + 255) / 256, 256, 0, stream>>>(edges, last_edge);
    k_relsrc<<<(NN + 255) / 256, 256, 0, stream>>>(edges, last_edge, relv, srcv);
    k_main<<<NREL * BPR + NSELF, 512, 0, stream>>>(h, weight, wself, relv, srcv, out);
}

// Round 3
// 48.886 us; speedup vs baseline: 1.9499x; 1.0683x over previous
//
#include <hip/hip_runtime.h>

#define NN 50000
#define NE 100000
#define NREL 64
#define D 64
#define BPR 16                               // blocks per relation
#define NPB ((NN + BPR - 1) / BPR)           // nodes scanned per rel-block = 3125
#define NSELF 64                             // self-only blocks
#define NPS ((NN + NSELF - 1) / NSELF)       // 782
#define LCAP 512

typedef unsigned long long u64;

// zero packed[] with 16B stores
__global__ void k_init(u64* __restrict__ packed) {
    int t = blockIdx.x * blockDim.x + threadIdx.x;
    if (t * 2 + 1 < NN) {
        reinterpret_cast<ulonglong2*>(packed)[t] = ulonglong2{0ull, 0ull};
    } else if (t * 2 < NN) {
        packed[t * 2] = 0ull;
    }
}

// one 64-bit atomicMax per edge: key = (e+1)<<22 | rel<<16 | src
__global__ void k_scatter(const int* __restrict__ edges, u64* __restrict__ packed) {
    int e = blockIdx.x * blockDim.x + threadIdx.x;
    if (e < NE) {
        int s = edges[e * 3 + 0];
        int r = edges[e * 3 + 1];
        int d = edges[e * 3 + 2];
        u64 key = ((u64)(e + 1) << 22) | ((u64)r << 16) | (u64)s;
        atomicMax(&packed[d], key);
    }
}

__device__ __forceinline__ float bcast(float x, int i) {
    return __int_as_float(__builtin_amdgcn_readlane(__float_as_int(x), i));
}

__global__ __launch_bounds__(512, 8) void k_main(
    const float* __restrict__ h, const float* __restrict__ weight,
    const float* __restrict__ wself, const u64* __restrict__ packed,
    float* __restrict__ out)
{
    __shared__ float lds_w[D * D];     // W[r]      (16 KiB)
    __shared__ float lds_ws[D * D];    // W_self    (16 KiB)
    __shared__ unsigned lds_list[LCAP];
    __shared__ int   lds_cnt;

    const int lane = threadIdx.x & 63;
    const int wave = threadIdx.x >> 6;
    const bool isRel = blockIdx.x < NREL * BPR;

    if (threadIdx.x == 0) lds_cnt = 0;

    // stage W_self (all blocks need it)
    for (int t = threadIdx.x; t < D * D / 4; t += 512)
        reinterpret_cast<float4*>(lds_ws)[t] = reinterpret_cast<const float4*>(wself)[t];

    int r = -1, start, count;
    if (isRel) {
        r = blockIdx.x / BPR;
        int c = blockIdx.x % BPR;
        start = c * NPB;
        count = min(NPB, NN - start);
        const float4* wsrc = reinterpret_cast<const float4*>(weight + (size_t)r * D * D);
        for (int t = threadIdx.x; t < D * D / 4; t += 512)
            reinterpret_cast<float4*>(lds_w)[t] = wsrc[t];
    } else {
        int c = blockIdx.x - NREL * BPR;
        start = c * NPS;
        count = min(NPS, NN - start);
        if (count < 0) count = 0;
    }
    __syncthreads();

    // scan phase: collect matching nodes (+src) into LDS list
    for (int t = threadIdx.x; t < count; t += 512) {
        int v = start + t;
        u64 key = packed[v];
        int rv = key ? (int)((key >> 16) & 63) : -1;
        if (rv == r) {
            int p = atomicAdd(&lds_cnt, 1);
            if (p < LCAP) lds_list[p] = ((unsigned)v << 16) | (unsigned)(key & 0xFFFF);
        }
    }
    __syncthreads();
    const int cnt = min(lds_cnt, LCAP);

    // process phase: 4 nodes per wave-iteration
    for (int gi = wave; gi * 4 < cnt; gi += 8) {
        const int g = gi * 4;
        const int nact = min(4, cnt - g);

        int v[4], s[4];
        #pragma unroll
        for (int j = 0; j < 4; ++j) {
            unsigned ent = lds_list[(j < nact) ? (g + j) : g];
            v[j] = (int)(ent >> 16);
            s[j] = (int)(ent & 0xFFFF);
        }

        float hv[4], hs[4];
        #pragma unroll
        for (int j = 0; j < 4; ++j) {
            hv[j] = h[(size_t)v[j] * D + lane];
            hs[j] = isRel ? h[(size_t)s[j] * D + lane] : 0.f;
        }

        float acc[4]  = {0.f, 0.f, 0.f, 0.f};
        float accS[4] = {0.f, 0.f, 0.f, 0.f};

        if (isRel) {
            #pragma unroll
            for (int i = 0; i < D; ++i) {
                const float w  = lds_w[i * D + lane];
                const float ws = lds_ws[i * D + lane];
                #pragma unroll
                for (int j = 0; j < 4; ++j) {
                    acc[j]  = fmaf(bcast(hs[j], i), w,  acc[j]);
                    accS[j] = fmaf(bcast(hv[j], i), ws, accS[j]);
                }
            }
        } else {
            #pragma unroll
            for (int i = 0; i < D; ++i) {
                const float ws = lds_ws[i * D + lane];
                #pragma unroll
                for (int j = 0; j < 4; ++j)
                    accS[j] = fmaf(bcast(hv[j], i), ws, accS[j]);
            }
        }

        #pragma unroll
        for (int j = 0; j < 4; ++j)
            if (j < nact) out[(size_t)v[j] * D + lane] = acc[j] + accS[j];
    }
}

extern "C" void kernel_launch(void* const* d_in, const int* in_sizes, int n_in,
                              void* d_out, int out_size, void* d_ws, size_t ws_size,
                              hipStream_t stream) {
    const float* h      = (const float*)d_in[0];
    const int*   edges  = (const int*)d_in[1];
    const float* weight = (const float*)d_in[2];
    const float* wself  = (const float*)d_in[3];
    float* out = (float*)d_out;

    u64* packed = (u64*)d_ws;   // NN * 8 B = 400 KB

    k_init<<<(NN / 2 + 255) / 256, 256, 0, stream>>>(packed);
    k_scatter<<<(NE + 255) / 256, 256, 0, stream>>>(edges, packed);
    k_main<<<NREL * BPR + NSELF, 512, 0, stream>>>(h, weight, wself, packed, out);
}